// Round 1
// baseline (278.640 us; speedup 1.0000x reference)
//
#include <hip/hip_runtime.h>
#include <cstdint>

// Fused MQA block: q = x@Wq+bq (16 heads), k/v = x@Wk/Wv (+b) shared head,
// out = softmax(q k^T / sqrt(128)) v, then @Wo + bo.
// B=2, S=2048, DIM=2048, H=16, D=128. fp32 in/out, bf16 MFMA internally.

#define SEQ 2048
#define NQKV 2304   // 2048 q + 128 k + 128 v
#define MTOT 4096   // B*S

typedef __attribute__((ext_vector_type(8))) short bf16x8;
typedef __attribute__((ext_vector_type(4))) float f32x4;

__device__ __forceinline__ unsigned short cvt_bf16(float f) {
  union { float f; unsigned int u; } v; v.f = f;
  unsigned int r = v.u + 0x7FFFu + ((v.u >> 16) & 1u);  // RNE
  return (unsigned short)(r >> 16);
}

typedef const __attribute__((address_space(1))) void gvoid;
typedef __attribute__((address_space(3))) void lvoid;
__device__ __forceinline__ void gload16(const void* g, void* l) {
  __builtin_amdgcn_global_load_lds((gvoid*)g, (lvoid*)l, 16, 0, 0);
}

// ---------------- prep kernels ----------------

__global__ __launch_bounds__(256) void cast_x_kernel(const float* __restrict__ x,
                                                     unsigned short* __restrict__ o) {
  long long i = ((long long)blockIdx.x * 256 + threadIdx.x) * 8;
  float4 a = *(const float4*)(x + i);
  float4 b = *(const float4*)(x + i + 4);
  union { bf16x8 v; unsigned short u[8]; } r;
  r.u[0] = cvt_bf16(a.x); r.u[1] = cvt_bf16(a.y); r.u[2] = cvt_bf16(a.z); r.u[3] = cvt_bf16(a.w);
  r.u[4] = cvt_bf16(b.x); r.u[5] = cvt_bf16(b.y); r.u[6] = cvt_bf16(b.z); r.u[7] = cvt_bf16(b.w);
  *(bf16x8*)(o + i) = r.v;
}

// dst[n][k] = src_sel[k][n - off], f32 -> bf16. Column ranges pick src0/1/2.
__global__ __launch_bounds__(256) void transpose_cast(
    const float* __restrict__ s0, const float* __restrict__ s1, const float* __restrict__ s2,
    int n1, int n2, int st0, int st1, int st2,
    unsigned short* __restrict__ dst, int K) {
  __shared__ float t[32][33];
  int n0 = blockIdx.x * 32, k0 = blockIdx.y * 32;
  const float* src; int off, stride;
  if (n0 < n1)      { src = s0; off = 0;  stride = st0; }
  else if (n0 < n2) { src = s1; off = n1; stride = st1; }
  else              { src = s2; off = n2; stride = st2; }
  int tx = threadIdx.x & 31, ty = threadIdx.x >> 5;
  #pragma unroll
  for (int r = 0; r < 4; r++)
    t[ty + r * 8][tx] = src[(size_t)(k0 + ty + r * 8) * stride + (n0 - off) + tx];
  __syncthreads();
  #pragma unroll
  for (int r = 0; r < 4; r++)
    dst[(size_t)(n0 + ty + r * 8) * K + k0 + tx] = cvt_bf16(t[tx][ty + r * 8]);
}

__global__ __launch_bounds__(256) void concat_bias(const float* __restrict__ bq,
    const float* __restrict__ bk, const float* __restrict__ bv, float* __restrict__ b1) {
  int i = blockIdx.x * 256 + threadIdx.x;
  if (i < NQKV) b1[i] = (i < 2048) ? bq[i] : (i < 2176 ? bk[i - 2048] : bv[i - 2176]);
}

// vT[b][d][j] = qkv[b*2048 + j][2176 + d] (bf16 transpose of V panel)
__global__ __launch_bounds__(256) void transpose_v(const unsigned short* __restrict__ qkv,
                                                   unsigned short* __restrict__ vT) {
  __shared__ unsigned short t[32][33];
  int bid = blockIdx.x;
  int dt = bid & 3, jt = (bid >> 2) & 63, b = bid >> 8;
  int j0 = jt * 32, d0 = dt * 32;
  int tx = threadIdx.x & 31, ty = threadIdx.x >> 5;
  #pragma unroll
  for (int r = 0; r < 4; r++)
    t[ty + r * 8][tx] = qkv[(size_t)(b * 2048 + j0 + ty + r * 8) * NQKV + 2176 + d0 + tx];
  __syncthreads();
  #pragma unroll
  for (int r = 0; r < 4; r++)
    vT[(size_t)(b * 128 + d0 + ty + r * 8) * 2048 + j0 + tx] = t[tx][ty + r * 8];
}

// ---------------- GEMM (m97-style 128x128 tile, B^T input) ----------------
// C[M][N] = A[M][K=2048] * BT[N][K]^T + bias[N].  BF16_OUT: bf16 store, else f32.
template <int BF16_OUT>
__global__ __launch_bounds__(256) void gemm_bt(const unsigned short* __restrict__ A,
    const unsigned short* __restrict__ BT, const float* __restrict__ bias,
    void* __restrict__ Cout, int N) {
  __shared__ unsigned short As[128 * 32];
  __shared__ unsigned short Bs[128 * 32];
  const int tid = threadIdx.x;
  const int l = tid & 63, w = tid >> 6;
  const int l15 = l & 15, g = l >> 4;
  const int wr = w >> 1, wc = w & 1;
  const int brow = blockIdx.x * 128, bcol = blockIdx.y * 128;
  const int K = 2048;
  const unsigned short* ga = A + (size_t)(brow + w * 32 + (l >> 2)) * K + (l & 3) * 8;
  const unsigned short* gb = BT + (size_t)(bcol + w * 32 + (l >> 2)) * K + (l & 3) * 8;
  unsigned short* lA = &As[w * 1024];
  unsigned short* lB = &Bs[w * 1024];
  f32x4 acc[4][4];
  const f32x4 z = {0.f, 0.f, 0.f, 0.f};
  #pragma unroll
  for (int i = 0; i < 4; i++)
    #pragma unroll
    for (int j = 0; j < 4; j++) acc[i][j] = z;

  for (int kt = 0; kt < K; kt += 32) {
    gload16(ga + kt, lA);
    gload16(ga + kt + 16 * K, lA + 512);
    gload16(gb + kt, lB);
    gload16(gb + kt + 16 * K, lB + 512);
    __syncthreads();
    bf16x8 af[4], bfr[4];
    #pragma unroll
    for (int mi = 0; mi < 4; mi++)
      af[mi] = *(const bf16x8*)&As[(wr * 64 + mi * 16 + l15) * 32 + g * 8];
    #pragma unroll
    for (int ni = 0; ni < 4; ni++)
      bfr[ni] = *(const bf16x8*)&Bs[(wc * 64 + ni * 16 + l15) * 32 + g * 8];
    __syncthreads();
    #pragma unroll
    for (int mi = 0; mi < 4; mi++)
      #pragma unroll
      for (int ni = 0; ni < 4; ni++)
        acc[mi][ni] = __builtin_amdgcn_mfma_f32_16x16x32_bf16(af[mi], bfr[ni], acc[mi][ni], 0, 0, 0);
  }
  float* Cf = (float*)Cout;
  unsigned short* Cb = (unsigned short*)Cout;
  #pragma unroll
  for (int ni = 0; ni < 4; ni++) {
    int col = bcol + wc * 64 + ni * 16 + l15;
    float bv = bias[col];
    #pragma unroll
    for (int mi = 0; mi < 4; mi++) {
      int row = brow + wr * 64 + mi * 16 + g * 4;
      #pragma unroll
      for (int r = 0; r < 4; r++) {
        float v = acc[mi][ni][r] + bv;
        if (BF16_OUT) Cb[(size_t)(row + r) * N + col] = cvt_bf16(v);
        else          Cf[(size_t)(row + r) * N + col] = v;
      }
    }
  }
}

// ---------------- fused MQA attention ----------------
// Block: 256 threads = 4 waves; wave owns 32 q-rows (2 x 16-row MFMA frags).
// Swapped QK^T: ST = mfma(K, Q) so softmax row i lives at lane (l&15)=i.
// K tile in LDS with XOR swizzle (G4); V^T tile in LDS padded to 40 (80B=5x16B rows).
__global__ __launch_bounds__(256) void attn_kernel(const unsigned short* __restrict__ qkv,
    const unsigned short* __restrict__ vT, unsigned short* __restrict__ aout) {
  __shared__ unsigned short Ks[32 * 128];
  __shared__ unsigned short Vs[128 * 40];
  const int tid = threadIdx.x, l = tid & 63, w = tid >> 6;
  const int l15 = l & 15, g = l >> 4;
  const int bid = blockIdx.x;
  const int qt = bid & 15, h = (bid >> 4) & 15, b = bid >> 8;
  const unsigned short* qb = qkv + (size_t)b * 2048 * NQKV;
  const unsigned short* vb = vT + (size_t)b * 128 * 2048;

  bf16x8 qf[2][4];
  const int qr = qt * 128 + w * 32;
  #pragma unroll
  for (int mi = 0; mi < 2; mi++)
    #pragma unroll
    for (int kk = 0; kk < 4; kk++)
      qf[mi][kk] = *(const bf16x8*)&qb[(size_t)(qr + mi * 16 + l15) * NQKV + h * 128 + kk * 32 + g * 8];

  f32x4 acc[2][8];
  const f32x4 z = {0.f, 0.f, 0.f, 0.f};
  #pragma unroll
  for (int mi = 0; mi < 2; mi++)
    #pragma unroll
    for (int d0 = 0; d0 < 8; d0++) acc[mi][d0] = z;
  float mr[2] = {-INFINITY, -INFINITY}, lr[2] = {0.f, 0.f};

  // staging: thread covers 2 x 16B chunks of each tile
  const int S0 = tid * 2, S1 = tid * 2 + 1;
  const int kr0 = S0 >> 4, ks0 = S0 & 15, kr1 = S1 >> 4, ks1 = S1 & 15;
  const unsigned short* gk0 = qb + (size_t)kr0 * NQKV + 2048 + ks0 * 8;
  const unsigned short* gk1 = qb + (size_t)kr1 * NQKV + 2048 + ks1 * 8;
  unsigned short* lk0 = (unsigned short*)((char*)Ks + kr0 * 256 + ((ks0 ^ (kr0 & 7)) << 4));
  unsigned short* lk1 = (unsigned short*)((char*)Ks + kr1 * 256 + ((ks1 ^ (kr1 & 7)) << 4));
  const int vd0 = S0 >> 2, vc0 = S0 & 3, vd1 = S1 >> 2, vc1 = S1 & 3;
  const unsigned short* gv0 = vb + (size_t)vd0 * 2048 + vc0 * 8;
  const unsigned short* gv1 = vb + (size_t)vd1 * 2048 + vc1 * 8;
  unsigned short* lv0 = &Vs[vd0 * 40 + vc0 * 8];
  unsigned short* lv1 = &Vs[vd1 * 40 + vc1 * 8];

  bf16x8 rk0 = *(const bf16x8*)gk0, rk1 = *(const bf16x8*)gk1;
  bf16x8 rv0 = *(const bf16x8*)gv0, rv1 = *(const bf16x8*)gv1;
  const float scale = 0.08838834764831845f;  // 1/sqrt(128)

  for (int jt = 0; jt < 64; jt++) {
    __syncthreads();
    *(bf16x8*)lk0 = rk0; *(bf16x8*)lk1 = rk1;
    *(bf16x8*)lv0 = rv0; *(bf16x8*)lv1 = rv1;
    __syncthreads();
    if (jt < 63) {  // T14: issue next tile's global loads under this tile's compute
      size_t ko = (size_t)(jt + 1) * 32 * NQKV;
      int vo = (jt + 1) * 32;
      rk0 = *(const bf16x8*)(gk0 + ko); rk1 = *(const bf16x8*)(gk1 + ko);
      rv0 = *(const bf16x8*)(gv0 + vo); rv1 = *(const bf16x8*)(gv1 + vo);
    }
    // ST[j][i] = sum_d K[j][d] Q[i][d]
    f32x4 st[2][2] = {{z, z}, {z, z}};
    #pragma unroll
    for (int kb = 0; kb < 2; kb++)
      #pragma unroll
      for (int kk = 0; kk < 4; kk++) {
        const int row = kb * 16 + l15;
        const int sl = kk * 4 + g;
        bf16x8 kf = *(const bf16x8*)((const char*)Ks + row * 256 + ((sl ^ (row & 7)) << 4));
        st[0][kb] = __builtin_amdgcn_mfma_f32_16x16x32_bf16(kf, qf[0][kk], st[0][kb], 0, 0, 0);
        st[1][kb] = __builtin_amdgcn_mfma_f32_16x16x32_bf16(kf, qf[1][kk], st[1][kb], 0, 0, 0);
      }
    #pragma unroll
    for (int mi = 0; mi < 2; mi++) {
      // lane holds S[q=l15][j = kb*16 + g*4 + r] — online softmax over row l15
      float sv[8];
      float vmax = -INFINITY;
      #pragma unroll
      for (int kb = 0; kb < 2; kb++)
        #pragma unroll
        for (int r = 0; r < 4; r++) {
          float x = st[mi][kb][r] * scale;
          sv[kb * 4 + r] = x;
          vmax = fmaxf(vmax, x);
        }
      vmax = fmaxf(vmax, __shfl_xor(vmax, 16));
      vmax = fmaxf(vmax, __shfl_xor(vmax, 32));
      float mn = fmaxf(mr[mi], vmax);
      float al = __expf(mr[mi] - mn);
      mr[mi] = mn;
      float rs = 0.f;
      #pragma unroll
      for (int i2 = 0; i2 < 8; i2++) { sv[i2] = __expf(sv[i2] - mn); rs += sv[i2]; }
      rs += __shfl_xor(rs, 16);
      rs += __shfl_xor(rs, 32);
      lr[mi] = lr[mi] * al + rs;
      // rescale acc (acc rows are g*4+r, alpha lives at l15-space -> shuffle)
      float a0 = __shfl(al, g * 4 + 0), a1 = __shfl(al, g * 4 + 1);
      float a2 = __shfl(al, g * 4 + 2), a3 = __shfl(al, g * 4 + 3);
      #pragma unroll
      for (int d0 = 0; d0 < 8; d0++) {
        acc[mi][d0][0] *= a0; acc[mi][d0][1] *= a1;
        acc[mi][d0][2] *= a2; acc[mi][d0][3] *= a3;
      }
      // P (D-layout) -> A-frag layout: lane needs P[l15][8g+e]
      union { bf16x8 v; unsigned short u[8]; } pw;
      #pragma unroll
      for (int e = 0; e < 8; e++) {
        int srcl = l15 + ((((g << 1) + (e >> 2)) & 3) << 4);
        float s0 = __shfl(sv[e & 3], srcl);
        float s1 = __shfl(sv[4 + (e & 3)], srcl);
        pw.u[e] = cvt_bf16(g < 2 ? s0 : s1);
      }
      bf16x8 pa = pw.v;
      #pragma unroll
      for (int d0 = 0; d0 < 8; d0++) {
        bf16x8 vf = *(const bf16x8*)&Vs[(d0 * 16 + l15) * 40 + g * 8];
        acc[mi][d0] = __builtin_amdgcn_mfma_f32_16x16x32_bf16(pa, vf, acc[mi][d0], 0, 0, 0);
      }
    }
  }
  // epilogue: divide by l (shuffle to acc-row space), store bf16
  #pragma unroll
  for (int mi = 0; mi < 2; mi++) {
    float i0 = 1.f / __shfl(lr[mi], g * 4 + 0);
    float i1 = 1.f / __shfl(lr[mi], g * 4 + 1);
    float i2 = 1.f / __shfl(lr[mi], g * 4 + 2);
    float i3 = 1.f / __shfl(lr[mi], g * 4 + 3);
    int grow = b * 2048 + qt * 128 + w * 32 + mi * 16 + g * 4;
    #pragma unroll
    for (int d0 = 0; d0 < 8; d0++) {
      size_t base = (size_t)grow * 2048 + h * 128 + d0 * 16 + l15;
      aout[base]            = cvt_bf16(acc[mi][d0][0] * i0);
      aout[base + 2048]     = cvt_bf16(acc[mi][d0][1] * i1);
      aout[base + 2 * 2048] = cvt_bf16(acc[mi][d0][2] * i2);
      aout[base + 3 * 2048] = cvt_bf16(acc[mi][d0][3] * i3);
    }
  }
}

// ---------------- launcher ----------------

extern "C" void kernel_launch(void* const* d_in, const int* in_sizes, int n_in,
                              void* d_out, int out_size, void* d_ws, size_t ws_size,
                              hipStream_t stream) {
  const float* x  = (const float*)d_in[0];
  const float* Wq = (const float*)d_in[1];
  const float* bq = (const float*)d_in[2];
  const float* Wk = (const float*)d_in[3];
  const float* bk = (const float*)d_in[4];
  const float* Wv = (const float*)d_in[5];
  const float* bv = (const float*)d_in[6];
  const float* Wo = (const float*)d_in[7];
  const float* bo = (const float*)d_in[8];
  float* out = (float*)d_out;

  char* ws = (char*)d_ws;
  size_t off = 0;
  auto alloc = [&](size_t bytes) -> void* {
    void* p = ws + off;
    off += (bytes + 255) & ~(size_t)255;
    return p;
  };
  unsigned short* xb    = (unsigned short*)alloc((size_t)MTOT * 2048 * 2);
  unsigned short* W1T   = (unsigned short*)alloc((size_t)NQKV * 2048 * 2);
  unsigned short* WoT   = (unsigned short*)alloc((size_t)2048 * 2048 * 2);
  float*          bias1 = (float*)alloc((size_t)NQKV * 4);
  unsigned short* qkv   = (unsigned short*)alloc((size_t)MTOT * NQKV * 2);
  unsigned short* vTb   = (unsigned short*)alloc((size_t)2 * 128 * 2048 * 2);
  unsigned short* aoutb = (unsigned short*)alloc((size_t)MTOT * 2048 * 2);
  if (off > ws_size) return;  // workspace too small — fail loudly via validation

  cast_x_kernel<<<4096, 256, 0, stream>>>(x, xb);
  transpose_cast<<<dim3(72, 64), 256, 0, stream>>>(Wq, Wk, Wv, 2048, 2176,
                                                   2048, 128, 128, W1T, 2048);
  transpose_cast<<<dim3(64, 64), 256, 0, stream>>>(Wo, Wo, Wo, 2048, 2048,
                                                   2048, 2048, 2048, WoT, 2048);
  concat_bias<<<9, 256, 0, stream>>>(bq, bk, bv, bias1);

  gemm_bt<1><<<dim3(32, 18), 256, 0, stream>>>(xb, W1T, bias1, qkv, NQKV);
  transpose_v<<<512, 256, 0, stream>>>(qkv, vTb);
  attn_kernel<<<512, 256, 0, stream>>>(qkv, vTb, aoutb);
  gemm_bt<0><<<dim3(32, 16), 256, 0, stream>>>(aoutb, WoT, bo, out, 2048);
}

// Round 2
// 246.123 us; speedup vs baseline: 1.1321x; 1.1321x over previous
//
#include <hip/hip_runtime.h>
#include <cstdint>

// Fused MQA block: q = x@Wq+bq (16 heads), k/v = x@Wk/Wv (+b) shared head,
// out = softmax(q k^T / sqrt(128)) v, then @Wo + bo.
// B=2, S=2048, DIM=2048, H=16, D=128. fp32 in/out, bf16 MFMA internally.

#define SEQ 2048
#define NQKV 2304   // 2048 q + 128 k + 128 v
#define MTOT 4096   // B*S

typedef __attribute__((ext_vector_type(8))) short bf16x8;
typedef __attribute__((ext_vector_type(4))) float f32x4;
typedef __attribute__((ext_vector_type(16))) float f32x16;

__device__ __forceinline__ unsigned short cvt_bf16(float f) {
  union { float f; unsigned int u; } v; v.f = f;
  unsigned int r = v.u + 0x7FFFu + ((v.u >> 16) & 1u);  // RNE
  return (unsigned short)(r >> 16);
}

__device__ __forceinline__ unsigned cvt_pk_bf16(float lo, float hi_) {
  unsigned r;
  asm("v_cvt_pk_bf16_f32 %0, %1, %2" : "=v"(r) : "v"(lo), "v"(hi_));
  return r;
}

// a' = {a.lo32lanes, b.lo32lanes}; b' = {a.hi32lanes, b.hi32lanes}
__device__ __forceinline__ void plane_swap(unsigned &a, unsigned &b) {
  asm volatile("v_permlane32_swap_b32 %0, %1" : "+v"(a), "+v"(b));
}

__device__ __forceinline__ float exp2_(float x) {
#if __has_builtin(__builtin_amdgcn_exp2f)
  return __builtin_amdgcn_exp2f(x);
#else
  return exp2f(x);
#endif
}

typedef const __attribute__((address_space(1))) void gvoid;
typedef __attribute__((address_space(3))) void lvoid;
__device__ __forceinline__ void gload16(const void* g, void* l) {
  __builtin_amdgcn_global_load_lds((gvoid*)g, (lvoid*)l, 16, 0, 0);
}

// ---------------- prep kernels ----------------

__global__ __launch_bounds__(256) void cast_x_kernel(const float* __restrict__ x,
                                                     unsigned short* __restrict__ o) {
  long long i = ((long long)blockIdx.x * 256 + threadIdx.x) * 8;
  float4 a = *(const float4*)(x + i);
  float4 b = *(const float4*)(x + i + 4);
  union { bf16x8 v; unsigned short u[8]; } r;
  r.u[0] = cvt_bf16(a.x); r.u[1] = cvt_bf16(a.y); r.u[2] = cvt_bf16(a.z); r.u[3] = cvt_bf16(a.w);
  r.u[4] = cvt_bf16(b.x); r.u[5] = cvt_bf16(b.y); r.u[6] = cvt_bf16(b.z); r.u[7] = cvt_bf16(b.w);
  *(bf16x8*)(o + i) = r.v;
}

// dst[n][k] = src_sel[k][n - off], f32 -> bf16. Column ranges pick src0/1/2.
__global__ __launch_bounds__(256) void transpose_cast(
    const float* __restrict__ s0, const float* __restrict__ s1, const float* __restrict__ s2,
    int n1, int n2, int st0, int st1, int st2,
    unsigned short* __restrict__ dst, int K) {
  __shared__ float t[32][33];
  int n0 = blockIdx.x * 32, k0 = blockIdx.y * 32;
  const float* src; int off, stride;
  if (n0 < n1)      { src = s0; off = 0;  stride = st0; }
  else if (n0 < n2) { src = s1; off = n1; stride = st1; }
  else              { src = s2; off = n2; stride = st2; }
  int tx = threadIdx.x & 31, ty = threadIdx.x >> 5;
  #pragma unroll
  for (int r = 0; r < 4; r++)
    t[ty + r * 8][tx] = src[(size_t)(k0 + ty + r * 8) * stride + (n0 - off) + tx];
  __syncthreads();
  #pragma unroll
  for (int r = 0; r < 4; r++)
    dst[(size_t)(n0 + ty + r * 8) * K + k0 + tx] = cvt_bf16(t[tx][ty + r * 8]);
}

__global__ __launch_bounds__(256) void concat_bias(const float* __restrict__ bq,
    const float* __restrict__ bk, const float* __restrict__ bv, float* __restrict__ b1) {
  int i = blockIdx.x * 256 + threadIdx.x;
  if (i < NQKV) b1[i] = (i < 2048) ? bq[i] : (i < 2176 ? bk[i - 2048] : bv[i - 2176]);
}

// vT[b][d][j] = qkv[b*2048 + j][2176 + d] (bf16 transpose of V panel)
__global__ __launch_bounds__(256) void transpose_v(const unsigned short* __restrict__ qkv,
                                                   unsigned short* __restrict__ vT) {
  __shared__ unsigned short t[32][33];
  int bid = blockIdx.x;
  int dt = bid & 3, jt = (bid >> 2) & 63, b = bid >> 8;
  int j0 = jt * 32, d0 = dt * 32;
  int tx = threadIdx.x & 31, ty = threadIdx.x >> 5;
  #pragma unroll
  for (int r = 0; r < 4; r++)
    t[ty + r * 8][tx] = qkv[(size_t)(b * 2048 + j0 + ty + r * 8) * NQKV + 2176 + d0 + tx];
  __syncthreads();
  #pragma unroll
  for (int r = 0; r < 4; r++)
    vT[(size_t)(b * 128 + d0 + ty + r * 8) * 2048 + j0 + tx] = t[tx][ty + r * 8];
}

// ---------------- GEMM (m97-style 128x128 tile, B^T input) ----------------
// C[M][N] = A[M][K=2048] * BT[N][K]^T + bias[N].  BF16_OUT: bf16 store, else f32.
template <int BF16_OUT>
__global__ __launch_bounds__(256) void gemm_bt(const unsigned short* __restrict__ A,
    const unsigned short* __restrict__ BT, const float* __restrict__ bias,
    void* __restrict__ Cout, int N) {
  __shared__ unsigned short As[128 * 32];
  __shared__ unsigned short Bs[128 * 32];
  const int tid = threadIdx.x;
  const int l = tid & 63, w = tid >> 6;
  const int l15 = l & 15, g = l >> 4;
  const int wr = w >> 1, wc = w & 1;
  const int brow = blockIdx.x * 128, bcol = blockIdx.y * 128;
  const int K = 2048;
  const unsigned short* ga = A + (size_t)(brow + w * 32 + (l >> 2)) * K + (l & 3) * 8;
  const unsigned short* gb = BT + (size_t)(bcol + w * 32 + (l >> 2)) * K + (l & 3) * 8;
  unsigned short* lA = &As[w * 1024];
  unsigned short* lB = &Bs[w * 1024];
  f32x4 acc[4][4];
  const f32x4 z = {0.f, 0.f, 0.f, 0.f};
  #pragma unroll
  for (int i = 0; i < 4; i++)
    #pragma unroll
    for (int j = 0; j < 4; j++) acc[i][j] = z;

  for (int kt = 0; kt < K; kt += 32) {
    gload16(ga + kt, lA);
    gload16(ga + kt + 16 * K, lA + 512);
    gload16(gb + kt, lB);
    gload16(gb + kt + 16 * K, lB + 512);
    __syncthreads();
    bf16x8 af[4], bfr[4];
    #pragma unroll
    for (int mi = 0; mi < 4; mi++)
      af[mi] = *(const bf16x8*)&As[(wr * 64 + mi * 16 + l15) * 32 + g * 8];
    #pragma unroll
    for (int ni = 0; ni < 4; ni++)
      bfr[ni] = *(const bf16x8*)&Bs[(wc * 64 + ni * 16 + l15) * 32 + g * 8];
    __syncthreads();
    #pragma unroll
    for (int mi = 0; mi < 4; mi++)
      #pragma unroll
      for (int ni = 0; ni < 4; ni++)
        acc[mi][ni] = __builtin_amdgcn_mfma_f32_16x16x32_bf16(af[mi], bfr[ni], acc[mi][ni], 0, 0, 0);
  }
  float* Cf = (float*)Cout;
  unsigned short* Cb = (unsigned short*)Cout;
  #pragma unroll
  for (int ni = 0; ni < 4; ni++) {
    int col = bcol + wc * 64 + ni * 16 + l15;
    float bv = bias[col];
    #pragma unroll
    for (int mi = 0; mi < 4; mi++) {
      int row = brow + wr * 64 + mi * 16 + g * 4;
      #pragma unroll
      for (int r = 0; r < 4; r++) {
        float v = acc[mi][ni][r] + bv;
        if (BF16_OUT) Cb[(size_t)(row + r) * N + col] = cvt_bf16(v);
        else          Cf[(size_t)(row + r) * N + col] = v;
      }
    }
  }
}

// ---------------- fused MQA attention (32x32 swapped structure) ----------------
// Block: 256 threads = 4 waves; wave owns QBLK=32 q-rows via 32x32x16 MFMA.
// Swapped QK^T: st = mfma(K, Q) => lane holds P[j=crow(r,hi)][i=l&31]; softmax
// rows are in-lane (+1 shfl_xor(32) to merge halves). P->A-frag via
// cvt_pk_bf16 + v_permlane32_swap (T12). Defer-max rescale (T13, THR=8).
// K [64][128] and V^T [128][64] LDS tiles, XOR-chunk swizzle, staged with
// global_load_lds(16B) from pre-swizzled global addresses (m173 pattern).
__global__ __launch_bounds__(256) void attn_kernel(const unsigned short* __restrict__ qkv,
    const unsigned short* __restrict__ vT, unsigned short* __restrict__ aout) {
  __shared__ unsigned short Ks[64 * 128];  // row stride 128 shorts (256B, 16 chunks)
  __shared__ unsigned short Vs[128 * 64];  // row stride 64 shorts (128B, 8 chunks)
  const int tid = threadIdx.x, l = tid & 63, wq = tid >> 6;
  const int l31 = l & 31, hi = l >> 5, l7 = l & 7;
  const int bid = blockIdx.x;
  const int qt = bid & 15, h = (bid >> 4) & 15, b = bid >> 8;
  const unsigned short* qb = qkv + (size_t)b * 2048 * NQKV;
  const unsigned short* vb = vT + (size_t)b * 128 * 2048;

  // Q B-frags: qf[kt] = Q[i=l31][d = kt*16 + hi*8 + e]
  bf16x8 qf[8];
  {
    const unsigned short* qp = qb + (size_t)(qt * 128 + wq * 32 + l31) * NQKV + h * 128 + hi * 8;
    #pragma unroll
    for (int kt = 0; kt < 8; kt++) qf[kt] = *(const bf16x8*)(qp + kt * 16);
  }

  // staging: wave wq covers K rows [wq*16, wq*16+16) and V rows [wq*32, wq*32+32).
  // global source pre-swizzled: LDS[row][c] gets global chunk c ^ (row&7).
  const unsigned short* gk[4];
  const unsigned short* gv[4];
  #pragma unroll
  for (int i = 0; i < 4; i++) {
    int krow = wq * 16 + i * 4 + (l >> 4), kc = l & 15;
    gk[i] = qb + (size_t)krow * NQKV + 2048 + ((kc ^ (krow & 7)) << 3);
    int vrow = wq * 32 + i * 8 + (l >> 3), vc = l & 7;
    gv[i] = vb + (size_t)vrow * 2048 + ((vc ^ (vrow & 7)) << 3);
  }

  f32x16 acc[4];
  #pragma unroll
  for (int d0 = 0; d0 < 4; d0++)
    #pragma unroll
    for (int r = 0; r < 16; r++) acc[d0][r] = 0.f;
  float m = -3.0e38f, lsum = 0.f;
  const float C2 = 0.12752299126446508f;  // (1/sqrt(128)) * log2(e)

  for (int jt = 0; jt < 32; jt++) {
    __syncthreads();  // all waves done reading LDS of previous tile
    #pragma unroll
    for (int i = 0; i < 4; i++) {
      gload16(gk[i], &Ks[wq * 2048 + i * 512]);
      gload16(gv[i], &Vs[wq * 2048 + i * 512]);
      gk[i] += 64 * NQKV;
      gv[i] += 64;
    }
    __syncthreads();  // drains vmcnt -> tile resident

    // QK^T: st[jb] = sum_d K[jb*32+row][d] * Q[i][d]
    f32x16 st[2];
    #pragma unroll
    for (int r = 0; r < 16; r++) { st[0][r] = 0.f; st[1][r] = 0.f; }
    #pragma unroll
    for (int jb = 0; jb < 2; jb++) {
      const int row = jb * 32 + l31;
      #pragma unroll
      for (int kt = 0; kt < 8; kt++) {
        const bf16x8 kf = *(const bf16x8*)&Ks[row * 128 + ((((kt << 1) | hi) ^ l7) << 3)];
        st[jb] = __builtin_amdgcn_mfma_f32_32x32x16_bf16(kf, qf[kt], st[jb], 0, 0, 0);
      }
    }

    // ---- online softmax (exp2 domain, raw-score max, defer-max rescale) ----
    float vmax = -3.0e38f;
    #pragma unroll
    for (int jb = 0; jb < 2; jb++)
      #pragma unroll
      for (int r = 0; r < 16; r++) vmax = fmaxf(vmax, st[jb][r]);
    vmax = fmaxf(vmax, __shfl_xor(vmax, 32));
    if (jt == 0) {
      m = vmax;
    } else if (!__all((vmax - m) * C2 <= 8.0f)) {
      float mn = fmaxf(m, vmax);
      float al = exp2_((m - mn) * C2);
      m = mn; lsum *= al;
      #pragma unroll
      for (int r = 0; r < 16; r++) {
        float av = __shfl(al, (r & 3) + 8 * (r >> 2) + 4 * hi);
        #pragma unroll
        for (int d0 = 0; d0 < 4; d0++) acc[d0][r] *= av;
      }
    }
    const float mc = m * C2;
    float rs = 0.f;
    #pragma unroll
    for (int jb = 0; jb < 2; jb++)
      #pragma unroll
      for (int r = 0; r < 16; r++) {
        float p = exp2_(st[jb][r] * C2 - mc);
        st[jb][r] = p; rs += p;
      }
    rs += __shfl_xor(rs, 32);
    lsum += rs;

    // ---- PV: pa[s] covers j = s*16 + hi*8 + e; acc[dblk] += pa * V^T-frag ----
    #pragma unroll
    for (int s = 0; s < 4; s++) {
      #define PP(c) (st[s >> 1][((s & 1) * 8) + (c)])
      unsigned a0 = cvt_pk_bf16(PP(0), PP(1));
      unsigned b0 = cvt_pk_bf16(PP(4), PP(5));
      plane_swap(a0, b0);   // a0 -> w0 (e0,e1), b0 -> w2 (e4,e5)
      unsigned a1 = cvt_pk_bf16(PP(2), PP(3));
      unsigned b1 = cvt_pk_bf16(PP(6), PP(7));
      plane_swap(a1, b1);   // a1 -> w1 (e2,e3), b1 -> w3 (e6,e7)
      #undef PP
      union { bf16x8 v; unsigned u[4]; } pa;
      pa.u[0] = a0; pa.u[1] = a1; pa.u[2] = b0; pa.u[3] = b1;
      #pragma unroll
      for (int d0 = 0; d0 < 4; d0++) {
        const int row = d0 * 32 + l31;
        const bf16x8 vf = *(const bf16x8*)&Vs[row * 64 + ((((s << 1) | hi) ^ l7) << 3)];
        acc[d0] = __builtin_amdgcn_mfma_f32_32x32x16_bf16(pa.v, vf, acc[d0], 0, 0, 0);
      }
    }
  }

  // epilogue: O[i = crow(r,hi)][d = d0*32 + l31] / lsum[i]
  float linv = 1.0f / lsum;
  const int qrow0 = b * 2048 + qt * 128 + wq * 32;
  #pragma unroll
  for (int r = 0; r < 16; r++) {
    const int crow = (r & 3) + 8 * (r >> 2) + 4 * hi;
    float li = __shfl(linv, crow);
    size_t rbase = (size_t)(qrow0 + crow) * 2048 + h * 128 + l31;
    #pragma unroll
    for (int d0 = 0; d0 < 4; d0++)
      aout[rbase + d0 * 32] = cvt_bf16(acc[d0][r] * li);
  }
}

// ---------------- launcher ----------------

extern "C" void kernel_launch(void* const* d_in, const int* in_sizes, int n_in,
                              void* d_out, int out_size, void* d_ws, size_t ws_size,
                              hipStream_t stream) {
  const float* x  = (const float*)d_in[0];
  const float* Wq = (const float*)d_in[1];
  const float* bq = (const float*)d_in[2];
  const float* Wk = (const float*)d_in[3];
  const float* bk = (const float*)d_in[4];
  const float* Wv = (const float*)d_in[5];
  const float* bv = (const float*)d_in[6];
  const float* Wo = (const float*)d_in[7];
  const float* bo = (const float*)d_in[8];
  float* out = (float*)d_out;

  char* ws = (char*)d_ws;
  size_t off = 0;
  auto alloc = [&](size_t bytes) -> void* {
    void* p = ws + off;
    off += (bytes + 255) & ~(size_t)255;
    return p;
  };
  unsigned short* xb    = (unsigned short*)alloc((size_t)MTOT * 2048 * 2);
  unsigned short* W1T   = (unsigned short*)alloc((size_t)NQKV * 2048 * 2);
  unsigned short* WoT   = (unsigned short*)alloc((size_t)2048 * 2048 * 2);
  float*          bias1 = (float*)alloc((size_t)NQKV * 4);
  unsigned short* qkv   = (unsigned short*)alloc((size_t)MTOT * NQKV * 2);
  unsigned short* vTb   = (unsigned short*)alloc((size_t)2 * 128 * 2048 * 2);
  unsigned short* aoutb = (unsigned short*)alloc((size_t)MTOT * 2048 * 2);
  if (off > ws_size) return;  // workspace too small — fail loudly via validation

  cast_x_kernel<<<4096, 256, 0, stream>>>(x, xb);
  transpose_cast<<<dim3(72, 64), 256, 0, stream>>>(Wq, Wk, Wv, 2048, 2176,
                                                   2048, 128, 128, W1T, 2048);
  transpose_cast<<<dim3(64, 64), 256, 0, stream>>>(Wo, Wo, Wo, 2048, 2048,
                                                   2048, 2048, 2048, WoT, 2048);
  concat_bias<<<9, 256, 0, stream>>>(bq, bk, bv, bias1);

  gemm_bt<1><<<dim3(32, 18), 256, 0, stream>>>(xb, W1T, bias1, qkv, NQKV);
  transpose_v<<<512, 256, 0, stream>>>(qkv, vTb);
  attn_kernel<<<512, 256, 0, stream>>>(qkv, vTb, aoutb);
  gemm_bt<0><<<dim3(32, 16), 256, 0, stream>>>(aoutb, WoT, bo, out, 2048);
}